// Round 11
// baseline (13.832 us; speedup 1.0000x reference)
//
#include <hip/hip_runtime.h>
#include <hip/hip_bf16.h>

#define CC 16     // hidden states
#define MM 32     // label alphabet
#define NGEN 16   // generators
#define TLP 17    // padded LDS stride for T table
#define GPB 8     // graphs per block in K2 (one per wave)

// K1: ONE 512-thread block computes the 32x16 table
//   T[m][g] = sum_c (num[c]/s)*log(num[c]), num[c] = smPi[c][g]*smB[c][m][g]
// via log(num[c]) = Pi[c][g] + B[c][m][g] - log dPi[g] - log dB[c][g]
// (272 logf equiv., mostly FMA). Reads only 2.3 KB (B, Pi).
// NOTE (R9 lesson): never single-dispatch this with a spin-flag —
// cross-XCD release/acquire visibility costs ~50us on MI355X.
__global__ void __launch_bounds__(512) cgmm_table_kernel(
        const float* __restrict__ B,
        const float* __restrict__ Pi,
        float* __restrict__ T) {
    __shared__ float dBs[CC * NGEN];
    __shared__ float ePiS[CC * NGEN];
    __shared__ float dPiS[NGEN];
    __shared__ float Acg[CC * NGEN];   // ePi/(dPi*dB)
    __shared__ float Lcg[CC * NGEN];   // Pi - log dPi - log dB

    const int tid = threadIdx.x;

    if (tid < CC * NGEN) {
        const int c = tid >> 4, g = tid & 15;
        float s = 0.f;
        #pragma unroll
        for (int m = 0; m < MM; ++m)
            s += expf(B[(c * MM + m) * NGEN + g]);
        dBs[tid] = s;
    } else if (tid < 2 * CC * NGEN) {
        ePiS[tid - CC * NGEN] = expf(Pi[tid - CC * NGEN]);
    }
    __syncthreads();
    if (tid < NGEN) {
        float s = 0.f;
        #pragma unroll
        for (int c = 0; c < CC; ++c) s += ePiS[c * NGEN + tid];
        dPiS[tid] = s;
    }
    __syncthreads();
    if (tid < CC * NGEN) {
        const int g = tid & 15;
        Acg[tid] = ePiS[tid] / (dPiS[g] * dBs[tid]);
        Lcg[tid] = Pi[tid] - logf(dPiS[g]) - logf(dBs[tid]);
    }
    __syncthreads();
    {
        const int m = tid >> 4;            // 0..31
        const int g = tid & 15;            // 0..15
        float ssum = 0.f, lsum = 0.f;
        #pragma unroll
        for (int cc = 0; cc < CC; ++cc) {
            const float b  = B[(cc * MM + m) * NGEN + g];
            const float ne = Acg[cc * NGEN + g] * expf(b);
            ssum += ne;
            lsum += ne * (Lcg[cc * NGEN + g] + b);
        }
        T[m * NGEN + g] = lsum / ssum;
    }
}

// K2: 8 graphs per 512-thread block, one per wave.
//  (1) per-wave dual 32-ary ballot lower_bound on sorted batch (lanes 0-31:
//      start, 32-63: end) — probes TLP-hidden across 20 waves/CU (R8 evidence)
//  (2) exact 32-bin label histogram, fully-coalesced 64-node rounds
//      (integer LDS atomics -> order-independent -> deterministic)
//  (3) combine out[g] = -sum_m cnt[m]*T[m][g] (same order as R6 -> absmax 4.0)
__global__ void __launch_bounds__(512) cgmm_graph_kernel(
        const int* __restrict__ x,
        const int* __restrict__ batch,
        const float* __restrict__ T,
        float* __restrict__ out,
        int n_nodes, int n_graphs) {
    __shared__ float Tl[MM * TLP];
    __shared__ int hist[GPB][MM];

    const int tid  = threadIdx.x;
    const int wave = tid >> 6;
    const int lane = tid & 63;
    const int gid  = blockIdx.x * GPB + wave;

    const float tval = T[tid];             // issue early; lands in Tl below
    if (lane < MM) hist[wave][lane] = 0;

    if (gid < n_graphs) {
        // (1) dual ballot 32-ary lower_bound
        const int half = lane >> 5;
        const int li   = lane & 31;
        const int target = gid + half;

        int lo = 0, hi = n_nodes;
        while (hi - lo > 32) {
            const int step = (hi - lo) >> 5;           // >= 1
            const int p = lo + li * step;              // max p < hi
            const bool c = batch[p] < target;
            const unsigned mask = (unsigned)(__ballot(c) >> (half << 5));
            const int k = __popc(mask);                // monotone prefix
            if (k == 0) {
                hi = lo;
            } else {
                const int nhi = (k < 32) ? (lo + k * step) : hi;
                lo = lo + (k - 1) * step + 1;
                hi = nhi;
            }
        }
        int bound;
        {
            const int p = lo + li;
            const bool c = (p < hi) && (batch[p] < target);
            const unsigned mask = (unsigned)(__ballot(c) >> (half << 5));
            bound = lo + __popc(mask);
        }
        const int start = __shfl(bound, 0);
        const int end   = __shfl(bound, 32);

        // (2) per-wave coalesced histogram (per-wave LDS ops are in-order)
        for (int n = start + lane; n < end; n += 64)
            atomicAdd(&hist[wave][x[n]], 1);
    }

    Tl[(tid >> 4) * TLP + (tid & 15)] = tval;   // 512 cells / 512 threads
    __syncthreads();   // Tl visible to all waves; hist ds_adds complete

    if (gid < n_graphs) {
        // (3) combine: lane = g + 16*q, q owns m = q*8 .. q*8+7
        const int g = lane & 15;
        const int q = lane >> 4;
        float acc = 0.f;
        #pragma unroll
        for (int j = 0; j < 8; ++j) {
            const int m = q * 8 + j;
            acc += (float)hist[wave][m] * Tl[m * TLP + g];
        }
        acc += __shfl_down(acc, 32);
        acc += __shfl_down(acc, 16);
        if (lane < NGEN) out[gid * NGEN + lane] = -acc;
    }
}

extern "C" void kernel_launch(void* const* d_in, const int* in_sizes, int n_in,
                              void* d_out, int out_size, void* d_ws, size_t ws_size,
                              hipStream_t stream) {
    const int* x     = (const int*)d_in[0];
    // d_in[1] = edge_index : unused by layer 0 (never read)
    const int* batch = (const int*)d_in[2];
    const float* B   = (const float*)d_in[3];
    const float* Pi  = (const float*)d_in[4];
    float* out       = (float*)d_out;
    float* T         = (float*)d_ws;   // 512 floats

    const int n_nodes  = in_sizes[0];
    const int n_graphs = out_size / NGEN;

    hipLaunchKernelGGL(cgmm_table_kernel, dim3(1), dim3(512), 0, stream,
                       B, Pi, T);
    hipLaunchKernelGGL(cgmm_graph_kernel,
                       dim3((n_graphs + GPB - 1) / GPB), dim3(512), 0, stream,
                       x, batch, T, out, n_nodes, n_graphs);
}

// Round 12
// 12.386 us; speedup vs baseline: 1.1168x; 1.1168x over previous
//
#include <hip/hip_runtime.h>
#include <hip/hip_bf16.h>

#define CC 16     // hidden states
#define MM 32     // label alphabet
#define NGEN 16   // generators
#define TLP 17    // padded LDS stride for T table
#define GPB 8     // graphs per block in K2 (one per wave)

// Structure-space results (R5-R11): this two-dispatch form is the floor.
//   {scan+table K1, histogram K2} : 12.54-12.60 us  (R6/R8/R10 - THIS)
//   {fused single dispatch}       : 14.0-15.5 us    (R5/R7 - per-block tax)
//   {flag producer/consumer}      : 54.8 us         (R9 - cross-XCD spin)
//   {table-only K1, search in K2} : 13.83 us        (R11 - search not hidden)
// Kernel work ~3-4 us; remainder is dispatch/replay fixed cost.

// K1: Block 0 computes the 32x16 table T:
//   T[m][g] = sum_c (num[c]/s)*log(num[c]), num[c] = smPi[c][g]*smB[c][m][g]
// via log(num[c]) = Pi[c][g] + B[c][m][g] - log dPi[g] - log dB[c][g]
// (272 logf total). Blocks 1.. scan sorted batch, writing
// offs[gph] = lower_bound(batch, gph) for gph in [0, n_graphs].
__global__ void __launch_bounds__(256) cgmm_prep_kernel(
        const float* __restrict__ B,
        const float* __restrict__ Pi,
        const int* __restrict__ batch,
        float* __restrict__ T,
        int* __restrict__ offs,
        int n_nodes, int n_graphs) {
    if (blockIdx.x == 0) {
        __shared__ float E[CC][MM][NGEN];   // exp(B), 32 KB
        __shared__ float Acg[CC][NGEN];     // ePi/(dPi*dB)
        __shared__ float Lcg[CC][NGEN];     // Pi - log dPi - log dB
        __shared__ float ePi[CC][NGEN];
        __shared__ float dPi[NGEN];

        const int tid = threadIdx.x;        // 0..255
        const int c = tid >> 4, g = tid & 15;

        float s = 0.f;
        #pragma unroll
        for (int m = 0; m < MM; ++m) {
            const float e = expf(B[(c * MM + m) * NGEN + g]);
            E[c][m][g] = e;
            s += e;
        }
        const float dB = s;
        ePi[c][g] = expf(Pi[c * NGEN + g]);
        __syncthreads();
        if (tid < NGEN) {
            float t = 0.f;
            #pragma unroll
            for (int cc = 0; cc < CC; ++cc) t += ePi[cc][tid];
            dPi[tid] = t;
        }
        __syncthreads();
        Acg[c][g] = ePi[c][g] / (dPi[g] * dB);
        Lcg[c][g] = Pi[c * NGEN + g] - logf(dPi[g]) - logf(dB);
        __syncthreads();

        #pragma unroll
        for (int r = 0; r < 2; ++r) {
            const int m = (tid >> 4) + r * 16;
            float ssum = 0.f, lsum = 0.f;
            #pragma unroll
            for (int cc = 0; cc < CC; ++cc) {
                const float ne = Acg[cc][g] * E[cc][m][g];
                ssum += ne;
                lsum += ne * (Lcg[cc][g] + B[(cc * MM + m) * NGEN + g]);
            }
            T[m * NGEN + g] = lsum / ssum;
        }
    } else {
        // boundary scan: offs[gph] = first n with batch[n] >= gph
        const int idx = (blockIdx.x - 1) * blockDim.x + threadIdx.x;
        const int stride = (gridDim.x - 1) * blockDim.x;
        for (int n = idx; n < n_nodes; n += stride) {
            const int b = batch[n];
            const int prev = (n == 0) ? -1 : batch[n - 1];
            for (int gph = prev + 1; gph <= b; ++gph) offs[gph] = n;
            if (n == n_nodes - 1)
                for (int gph = b + 1; gph <= n_graphs; ++gph) offs[gph] = n_nodes;
        }
    }
}

// K2: 8 graphs per 512-thread block, one per wave. Per wave: build an exact
// 32-bin label histogram with FULLY COALESCED 64-node iterations (LDS
// atomics; integer -> order-independent -> deterministic), then combine
// out[g] = -sum_m cnt[m]*T[m][g] (lane = g + 16*q, q owns 8 m's; 2 shuffles).
__global__ void __launch_bounds__(512) cgmm_graph_kernel(
        const int* __restrict__ x,
        const int* __restrict__ offs,
        const float* __restrict__ T,
        float* __restrict__ out,
        int n_graphs) {
    __shared__ float Tl[MM * TLP];
    __shared__ int hist[GPB][MM];

    const int tid  = threadIdx.x;
    const int wave = tid >> 6;
    const int lane = tid & 63;
    const int gid  = blockIdx.x * GPB + wave;

    if (tid < MM * NGEN)
        Tl[(tid >> 4) * TLP + (tid & 15)] = T[tid];
    if (lane < MM)
        hist[wave][lane] = 0;
    // per-wave LDS ops are in-order; histogram needs no cross-wave sync.

    int start = 0, end = 0;
    if (gid < n_graphs) {
        start = offs[gid];
        end   = offs[gid + 1];
    }
    for (int n = start + lane; n < end; n += 64)
        atomicAdd(&hist[wave][x[n]], 1);

    __syncthreads();   // Tl staged across waves; hist ds_adds complete

    if (gid < n_graphs) {
        const int g = lane & 15;
        const int q = lane >> 4;          // 0..3, owns m = q*8 .. q*8+7
        float acc = 0.f;
        #pragma unroll
        for (int j = 0; j < 8; ++j) {
            const int m = q * 8 + j;
            acc += (float)hist[wave][m] * Tl[m * TLP + g];
        }
        acc += __shfl_down(acc, 32);
        acc += __shfl_down(acc, 16);
        if (lane < NGEN) out[gid * NGEN + lane] = -acc;
    }
}

extern "C" void kernel_launch(void* const* d_in, const int* in_sizes, int n_in,
                              void* d_out, int out_size, void* d_ws, size_t ws_size,
                              hipStream_t stream) {
    const int* x     = (const int*)d_in[0];
    // d_in[1] = edge_index : unused by layer 0 (never read)
    const int* batch = (const int*)d_in[2];
    const float* B   = (const float*)d_in[3];
    const float* Pi  = (const float*)d_in[4];
    float* out       = (float*)d_out;
    float* T         = (float*)d_ws;                 // 512 floats
    int*   offs      = (int*)((char*)d_ws + 4096);   // n_graphs+1 ints

    const int n_nodes  = in_sizes[0];
    const int n_graphs = out_size / NGEN;

    hipLaunchKernelGGL(cgmm_prep_kernel, dim3(256), dim3(256), 0, stream,
                       B, Pi, batch, T, offs, n_nodes, n_graphs);
    hipLaunchKernelGGL(cgmm_graph_kernel,
                       dim3((n_graphs + GPB - 1) / GPB), dim3(512), 0, stream,
                       x, offs, T, out, n_graphs);
}